// Round 16
// baseline (566.837 us; speedup 1.0000x reference)
//
#include <hip/hip_runtime.h>
#include <hip/hip_bf16.h>
#include <cstdint>
#include <cstddef>

typedef __hip_bfloat16 bf16;
typedef __bf16 bf16x8 __attribute__((ext_vector_type(8)));
typedef float f32x4 __attribute__((ext_vector_type(4)));

#define S_D 30
#define C_D 16
#define H_D 768
#define EPS_F 1e-5f

// ------------------------------------------------------------------
// prep: bf16 transposed weight concats + folded biases.
// K-order PERMUTED to match packed aggregate layout:
// Wcat  [768n x 3840k]: k<768 -> W_s;  k=768+kk*4+seg -> W_r[seg][kk]
// Wcat2 [768n x 2304k]: k<768 -> W_s;  k=768+kk*2+seg -> W_r[seg?2:0][kk]
// Wg    [768n x 1536k]: W_g^T (unpermuted)
// ------------------------------------------------------------------
__global__ __launch_bounds__(256) void prep_weights_k(
    const float* __restrict__ W_r, const float* __restrict__ b_r,
    const float* __restrict__ W_s, const float* __restrict__ b_s,
    const float* __restrict__ W_g,
    bf16* __restrict__ Wcat, bf16* __restrict__ Wg, bf16* __restrict__ Wcat2,
    float* __restrict__ bslot, float* __restrict__ bcls)
{
  int id = blockIdx.x*256 + threadIdx.x;
  const int n1 = 768*3840, n2 = 768*1536, n3 = 768*2304;
  if (id < n1) {
    int n = id / 3840, k = id % 3840;
    float w;
    if (k < 768) w = W_s[k*768 + n];
    else { int j = k - 768, kk = j >> 2, seg = j & 3;
           w = W_r[((size_t)seg*768 + kk)*768 + n]; }
    Wcat[id] = __float2bfloat16(w);
  } else if (id < n1 + n2) {
    int j = id - n1; int n = j / 1536, k = j % 1536;
    Wg[j] = __float2bfloat16(W_g[(size_t)k*768 + n]);
  } else if (id < n1 + n2 + n3) {
    int j = id - n1 - n2; int n = j / 2304, k = j % 2304;
    float w;
    if (k < 768) w = W_s[k*768 + n];
    else { int jj = k - 768, kk = jj >> 1, seg = jj & 1;
           w = W_r[((size_t)(seg ? 2 : 0)*768 + kk)*768 + n]; }
    Wcat2[j] = __float2bfloat16(w);
  } else if (id < n1 + n2 + n3 + 768) {
    int n = id - n1 - n2 - n3;
    bslot[n] = b_s[n] + b_r[n] + b_r[768+n] + b_r[2*768+n] + b_r[3*768+n];
    bcls[n]  = b_s[n] + b_r[n] + b_r[2*768+n];
  }
}

// ------------------------------------------------------------------
// layer-1 aggregation + init (R8 structure, unchanged).
// ------------------------------------------------------------------
__global__ __launch_bounds__(256) void agg1_k(
    const float* __restrict__ slots, const float* __restrict__ cls,
    const float* __restrict__ a_cur, const float* __restrict__ a_slot,
    const float* __restrict__ a_last, const float* __restrict__ a_dom,
    bf16* __restrict__ Gin, bf16* __restrict__ Zs, bf16* __restrict__ Zc,
    int b0, int rsBase)
{
  __shared__ float Lac[30*16], Lal[30*16];
  __shared__ float Las[30*32], Lad[30*32];
  __shared__ float LacT[16*32], LalT[16*32];
  __shared__ float ivr[4*32], ivc[2*16];
  const int lb = blockIdx.x, b = b0 + lb, tid = threadIdx.x;
  const float* ac  = a_cur  + (size_t)b*480;
  const float* as_ = a_slot + (size_t)b*900;
  const float* al  = a_last + (size_t)b*480;
  const float* ad  = a_dom  + (size_t)b*900;

  if (tid < 30) {
    float s1=0, s3=0;
    for (int c=0;c<16;c++){ s1+=ac[tid*16+c]; s3+=al[tid*16+c]; }
    ivr[tid] = 1.f/(s1+EPS_F); ivr[32+tid] = 1.f/(s3+EPS_F);
    float s2=0, s4=0;
    for (int j=0;j<30;j++){ s2+=as_[tid*30+j]; s4+=ad[tid*30+j]; }
    ivr[64+tid] = 1.f/(s2+EPS_F); ivr[96+tid] = 1.f/(s4+EPS_F);
  } else if (tid < 46) {
    int c = tid - 30; float s1=0, s3=0;
    for (int s=0;s<30;s++){ s1+=ac[s*16+c]; s3+=al[s*16+c]; }
    ivc[c] = 1.f/(s1+EPS_F); ivc[16+c] = 1.f/(s3+EPS_F);
  }
  __syncthreads();
  for (int i = tid; i < 480; i += 256) {
    int s = i >> 4;
    Lac[i] = ac[i]*ivr[s];
    Lal[i] = al[i]*ivr[32+s];
  }
  for (int i = tid; i < 960; i += 256) {
    int s = i >> 5, j = i & 31;
    Las[i] = (j < 30) ? as_[s*30+j]*ivr[64+s] : 0.f;
    Lad[i] = (j < 30) ? ad[s*30+j]*ivr[96+s] : 0.f;
  }
  for (int i = tid; i < 512; i += 256) {
    int c = i >> 5, s = i & 31;
    LacT[i] = (s < 30) ? ac[s*16+c]*ivc[c]    : 0.f;
    LalT[i] = (s < 30) ? al[s*16+c]*ivc[16+c] : 0.f;
  }
  __syncthreads();

  float xs[3][32], xc[3][16];
  #pragma unroll
  for (int j = 0; j < 3; ++j) {
    const int h = tid + j*256;
    #pragma unroll
    for (int s = 0; s < 30; ++s) xs[j][s] = slots[((size_t)b*30 + s)*768 + h];
    xs[j][30] = 0.f; xs[j][31] = 0.f;
    #pragma unroll
    for (int c = 0; c < 16; ++c) xc[j][c] = cls[((size_t)b*16 + c)*768 + h];
  }
  #pragma unroll
  for (int j = 0; j < 3; ++j) {
    const int h = tid + j*256;
    bf16* Gs = Gin + ((size_t)lb*30)*1536 + 768 + h;
    #pragma unroll
    for (int s = 0; s < 30; ++s) Gs[(size_t)s*1536] = __float2bfloat16(xs[j][s]);
    bf16* Gc = Gin + ((size_t)(rsBase + lb*16))*1536 + 768 + h;
    #pragma unroll
    for (int c = 0; c < 16; ++c) Gc[(size_t)c*1536] = __float2bfloat16(xc[j][c]);
  }

  #pragma unroll 2
  for (int s = 0; s < 30; ++s) {
    float a1[3] = {}, a2[3] = {}, a3[3] = {}, a4[3] = {};
    #pragma unroll
    for (int q = 0; q < 4; ++q) {
      float4 va = *(const float4*)&Lac[s*16 + q*4];
      float4 vl = *(const float4*)&Lal[s*16 + q*4];
      #pragma unroll
      for (int j = 0; j < 3; ++j) {
        a1[j] += va.x*xc[j][q*4] + va.y*xc[j][q*4+1] + va.z*xc[j][q*4+2] + va.w*xc[j][q*4+3];
        a3[j] += vl.x*xc[j][q*4] + vl.y*xc[j][q*4+1] + vl.z*xc[j][q*4+2] + vl.w*xc[j][q*4+3];
      }
    }
    #pragma unroll
    for (int q = 0; q < 8; ++q) {
      float4 vs = *(const float4*)&Las[s*32 + q*4];
      float4 vd = *(const float4*)&Lad[s*32 + q*4];
      #pragma unroll
      for (int j = 0; j < 3; ++j) {
        a2[j] += vs.x*xs[j][q*4] + vs.y*xs[j][q*4+1] + vs.z*xs[j][q*4+2] + vs.w*xs[j][q*4+3];
        a4[j] += vd.x*xs[j][q*4] + vd.y*xs[j][q*4+1] + vd.z*xs[j][q*4+2] + vd.w*xs[j][q*4+3];
      }
    }
    char* Zrow = (char*)Zs + (((size_t)lb*30 + s)*3072)*2;
    #pragma unroll
    for (int j = 0; j < 3; ++j) {
      const int h = tid + j*256;
      union { bf16 hv[4]; uint2 u; } p;
      p.hv[0] = __float2bfloat16(a1[j]);
      p.hv[1] = __float2bfloat16(a2[j]);
      p.hv[2] = __float2bfloat16(a3[j]);
      p.hv[3] = __float2bfloat16(a4[j]);
      *(uint2*)(Zrow + (size_t)h*8) = p.u;
    }
  }
  #pragma unroll 2
  for (int c = 0; c < 16; ++c) {
    float a1[3] = {}, a3[3] = {};
    #pragma unroll
    for (int q = 0; q < 8; ++q) {
      float4 va = *(const float4*)&LacT[c*32 + q*4];
      float4 vl = *(const float4*)&LalT[c*32 + q*4];
      #pragma unroll
      for (int j = 0; j < 3; ++j) {
        a1[j] += va.x*xs[j][q*4] + va.y*xs[j][q*4+1] + va.z*xs[j][q*4+2] + va.w*xs[j][q*4+3];
        a3[j] += vl.x*xs[j][q*4] + vl.y*xs[j][q*4+1] + vl.z*xs[j][q*4+2] + vl.w*xs[j][q*4+3];
      }
    }
    char* Zrow = (char*)Zc + (((size_t)lb*16 + c)*1536)*2;
    #pragma unroll
    for (int j = 0; j < 3; ++j) {
      const int h = tid + j*256;
      union { bf16 hv[2]; unsigned u; } p;
      p.hv[0] = __float2bfloat16(a1[j]);
      p.hv[1] = __float2bfloat16(a3[j]);
      *(unsigned*)(Zrow + (size_t)h*4) = p.u;
    }
  }
}

// ------------------------------------------------------------------
// layer-2 aggregation (cls rows only) from layer-1 slot state Xo (bf16).
// ------------------------------------------------------------------
__global__ __launch_bounds__(256) void agg2_k(
    const bf16* __restrict__ Xo,
    const float* __restrict__ a_cur, const float* __restrict__ a_last,
    bf16* __restrict__ Zc, int b0)
{
  __shared__ float LacT[16*32], LalT[16*32];
  __shared__ float ivc[2*16];
  const int lb = blockIdx.x, b = b0 + lb, tid = threadIdx.x;
  const float* ac = a_cur  + (size_t)b*480;
  const float* al = a_last + (size_t)b*480;
  if (tid < 16) {
    float s1=0, s3=0;
    for (int s=0;s<30;s++){ s1+=ac[s*16+tid]; s3+=al[s*16+tid]; }
    ivc[tid] = 1.f/(s1+EPS_F); ivc[16+tid] = 1.f/(s3+EPS_F);
  }
  __syncthreads();
  for (int i = tid; i < 512; i += 256) {
    int c = i >> 5, s = i & 31;
    LacT[i] = (s < 30) ? ac[s*16+c]*ivc[c]    : 0.f;
    LalT[i] = (s < 30) ? al[s*16+c]*ivc[16+c] : 0.f;
  }
  __syncthreads();

  float xs[3][32];
  #pragma unroll
  for (int j = 0; j < 3; ++j) {
    const int h = tid + j*256;
    #pragma unroll
    for (int s = 0; s < 30; ++s)
      xs[j][s] = __bfloat162float(Xo[((size_t)(lb*30 + s))*768 + h]);
    xs[j][30] = 0.f; xs[j][31] = 0.f;
  }
  #pragma unroll 2
  for (int c = 0; c < 16; ++c) {
    float a1[3] = {}, a3[3] = {};
    #pragma unroll
    for (int q = 0; q < 8; ++q) {
      float4 va = *(const float4*)&LacT[c*32 + q*4];
      float4 vl = *(const float4*)&LalT[c*32 + q*4];
      #pragma unroll
      for (int j = 0; j < 3; ++j) {
        a1[j] += va.x*xs[j][q*4] + va.y*xs[j][q*4+1] + va.z*xs[j][q*4+2] + va.w*xs[j][q*4+3];
        a3[j] += vl.x*xs[j][q*4] + vl.y*xs[j][q*4+1] + vl.z*xs[j][q*4+2] + vl.w*xs[j][q*4+3];
      }
    }
    char* Zrow = (char*)Zc + (((size_t)lb*16 + c)*1536)*2;
    #pragma unroll
    for (int j = 0; j < 3; ++j) {
      const int h = tid + j*256;
      union { bf16 hv[2]; unsigned u; } p;
      p.hv[0] = __float2bfloat16(a1[j]);
      p.hv[1] = __float2bfloat16(a3[j]);
      *(unsigned*)(Zrow + (size_t)h*4) = p.u;
    }
  }
}

// ------------------------------------------------------------------
// GEMM body: one BMxBN tile (BK=64) of A[M x K] @ Bt[768 x K]^T.
// Wave grid 2x2: each wave owns (BM/2 rows) x (BN/2 cols) ->
// AM=BM/32 a-frags, BNF=BN/32 b-frags per wave (R15's NaN was
// bfv[BNF*2] overrunning the B-tile; fixed to BNF).
// BM=BN=64, 1buf -> 16 KB LDS -> 8 blocks/CU (max TLP, the only
// lever that moved dur in R11-R14).
// T2 both-sides XOR swizzle. MODE 0 = 1buf split-K pointer staging;
// MODE 1 = legacy dbuf prefetch (small layer-2 grids).
// EPI 0: proj -> G left half = bf16(v + bias[col])
// EPI 1: gate -> Xo bf16; rows>=rsB also G2 right half (new cls x)
// EPI 2: gate -> out f32 (cls rows; skip c==0)
// ------------------------------------------------------------------
template<int BM, int BN, int K, int EPI, int LDA0, int LDA1, int SK, int MODE>
__device__ __forceinline__ void gemm_body(
    bf16* __restrict__ As, bf16* __restrict__ Bs, int wg,
    const bf16* __restrict__ A0, const bf16* __restrict__ A1,
    const bf16* __restrict__ Bt, bf16* __restrict__ G,
    bf16* __restrict__ G2, bf16* __restrict__ Xo, float* __restrict__ out,
    const float* __restrict__ bias, const float* __restrict__ bg,
    int b0, int rsB)
{
  constexpr int AM  = BM/32;                 // a-frags per wave (= A issues)
  constexpr int BNF = BN/32;                 // b-frags per wave (= B issues)
  constexpr int NBN = 768/BN;
  const int tid  = threadIdx.x;
  const int lane = tid & 63;
  const int wave = tid >> 6;
  const int wm = wave >> 1, wn = wave & 1;   // 2x2 wave grid
  const int bm = wg / NBN, bn = wg % NBN;

  const int swz = (((tid & 7) ^ ((tid >> 3) & 7))) << 3;   // elements
  const bf16* Ag0 = A0 + (size_t)(bm*BM + (tid>>3))*LDA0 + swz;
  const bf16* Ag1 = A1 + (size_t)(bm*BM + (tid>>3))*LDA1 + swz;
  const bf16* Bg  = Bt + (size_t)(bn*BN + (tid>>3))*K   + swz;
  const int ldsw = (wave*8)*64;              // wave-uniform LDS base

  f32x4 acc[AM][BNF] = {};
  constexpr int NT = K/64;

  auto compute = [&](int buf) {
    const bf16* Asb = As + buf*(BM*64);
    const bf16* Bsb = Bs + buf*(BN*64);
    #pragma unroll
    for (int ks = 0; ks < 64; ks += 32) {
      bf16x8 afv[AM], bfv[BNF];
      const int sa = ((((ks >> 3) + (lane >> 4)) ^ (lane & 7))) << 3;
      #pragma unroll
      for (int i = 0; i < AM; ++i) {
        int m = wm*(BM/2) + i*16 + (lane & 15);
        afv[i] = *(const bf16x8*)&Asb[m*64 + sa];
      }
      #pragma unroll
      for (int j = 0; j < BNF; ++j) {
        int n = wn*(BN/2) + j*16 + (lane & 15);
        bfv[j] = *(const bf16x8*)&Bsb[n*64 + sa];
      }
      #pragma unroll
      for (int i = 0; i < AM; ++i)
        #pragma unroll
        for (int j = 0; j < BNF; ++j)
          acc[i][j] = __builtin_amdgcn_mfma_f32_16x16x32_bf16(afv[i], bfv[j], acc[i][j], 0, 0, 0);
    }
  };

  if constexpr (MODE == 0) {
    // 1buf split-K pointer staging (R13 loop, BN-generalized)
    const bf16* aP[AM];
    const bf16* bP[BNF];
    #pragma unroll
    for (int p = 0; p < AM; ++p) aP[p] = Ag0 + (size_t)(p*32)*LDA0;
    #pragma unroll
    for (int p = 0; p < BNF; ++p) bP[p] = Bg + (size_t)(p*32)*K;

    auto step = [&]() {
      #pragma unroll
      for (int p = 0; p < AM; ++p) {
        __builtin_amdgcn_global_load_lds(
          (const __attribute__((address_space(1))) void*)aP[p],
          (__attribute__((address_space(3))) void*)(&As[ldsw + p*2048]), 16, 0, 0);
        aP[p] += 64;
      }
      #pragma unroll
      for (int p = 0; p < BNF; ++p) {
        __builtin_amdgcn_global_load_lds(
          (const __attribute__((address_space(1))) void*)bP[p],
          (__attribute__((address_space(3))) void*)(&Bs[ldsw + p*2048]), 16, 0, 0);
        bP[p] += 64;
      }
      __syncthreads();     // loads landed
      compute(0);
      __syncthreads();     // reads done before next overwrite
    };

    #pragma unroll 1
    for (int t = 0; t < SK/64; ++t) step();
    if constexpr (SK < K) {
      #pragma unroll
      for (int p = 0; p < AM; ++p) aP[p] = Ag1 + (size_t)(p*32)*LDA1;
      #pragma unroll 1
      for (int t = 0; t < (K - SK)/64; ++t) step();
    }
  } else {
    // legacy dbuf prefetch (__syncthreads drains) -- small layer-2 grids
    auto stage = [&](int buf, int kt) {
      #pragma unroll
      for (int p = 0; p < AM; ++p) {
        const bf16* asrc = (kt < SK) ? (Ag0 + (size_t)(p*32)*LDA0 + kt)
                                     : (Ag1 + (size_t)(p*32)*LDA1 + (kt - SK));
        __builtin_amdgcn_global_load_lds(
          (const __attribute__((address_space(1))) void*)asrc,
          (__attribute__((address_space(3))) void*)(&As[buf*(BM*64) + ldsw + p*2048]), 16, 0, 0);
      }
      #pragma unroll
      for (int p = 0; p < BNF; ++p) {
        __builtin_amdgcn_global_load_lds(
          (const __attribute__((address_space(1))) void*)(Bg + (size_t)(p*32)*K + kt),
          (__attribute__((address_space(3))) void*)(&Bs[buf*(BN*64) + ldsw + p*2048]), 16, 0, 0);
      }
    };
    stage(0, 0);
    __syncthreads();
    int cur = 0;
    #pragma unroll 1
    for (int t = 0; t < NT; ++t) {
      if (t + 1 < NT) stage(cur ^ 1, (t + 1)*64);
      compute(cur);
      __syncthreads();
      cur ^= 1;
    }
  }

  const int rbase = bm*BM + wm*(BM/2) + ((lane>>4)<<2);
  const int cbase = bn*BN + wn*(BN/2) + (lane & 15);
  #pragma unroll
  for (int i = 0; i < AM; ++i) {
    #pragma unroll
    for (int j = 0; j < BNF; ++j) {
      const int col = cbase + j*16;
      #pragma unroll
      for (int r2 = 0; r2 < 4; ++r2) {
        const int row = rbase + i*16 + r2;
        float v = acc[i][j][r2];
        if constexpr (EPI == 0) {
          G[(size_t)row*1536 + col] = __float2bfloat16(v + bias[col]);
        } else if constexpr (EPI == 1) {
          v += bg[col];
          float g = 1.f/(1.f + __expf(-v));
          float u = __bfloat162float(G[(size_t)row*1536 + col]);
          float x = __bfloat162float(G[(size_t)row*1536 + 768 + col]);
          bf16 nv = __float2bfloat16(fmaxf(u, 0.f)*g + x*(1.f - g));
          Xo[(size_t)row*H_D + col] = nv;
          if (row >= rsB)
            G2[((size_t)(row - rsB))*1536 + 768 + col] = nv;
        } else { // EPI == 2
          v += bg[col];
          float g = 1.f/(1.f + __expf(-v));
          float u = __bfloat162float(G[(size_t)row*1536 + col]);
          int bb = row >> 4, c = row & 15;
          if (c >= 1) {
            float x = __bfloat162float(Xo[(size_t)row*H_D + col]);
            out[((size_t)(b0 + bb)*15 + (c - 1))*H_D + col] =
                fmaxf(u, 0.f)*g + x*(1.f - g);
          }
        }
      }
    }
  }
}

// T1 bijective XCD-chunked swizzle (m204)
__device__ __forceinline__ int xcd_swizzle(int bid, int nwg) {
  const int q = nwg >> 3, r = nwg & 7;
  const int xcd = bid & 7, idx = bid >> 3;
  return (xcd < r ? xcd*(q+1) : r*(q+1) + (xcd-r)*q) + idx;
}

// Standalone GEMM kernel
template<int BM, int BN, int K, int EPI, int LDA0, int LDA1, int SK, int MODE>
__global__ __launch_bounds__(256) void gemm_k(
    const bf16* __restrict__ A0, const bf16* __restrict__ A1,
    const bf16* __restrict__ Bt, bf16* __restrict__ G,
    bf16* __restrict__ G2, bf16* __restrict__ Xo, float* __restrict__ out,
    const float* __restrict__ bias, const float* __restrict__ bg,
    int b0, int rsB)
{
  __shared__ __align__(16) bf16 As[(MODE ? 2 : 1)*BM*64];
  __shared__ __align__(16) bf16 Bs[(MODE ? 2 : 1)*BN*64];
  int wg = xcd_swizzle(blockIdx.x, gridDim.x);
  gemm_body<BM, BN, K, EPI, LDA0, LDA1, SK, MODE>(As, Bs, wg, A0, A1, Bt, G, G2,
                                                  Xo, out, bias, bg, b0, rsB);
}

// Merged layer-1 projection (BM=BN=64, 16 KB LDS -> 8 blocks/CU):
// blocks [0,nS) slot proj (K=3840), [nS, nS+nC) cls proj (K=2304).
__global__ __launch_bounds__(256) void proj1_k(
    const bf16* __restrict__ GinSx, const bf16* __restrict__ Zs,
    const bf16* __restrict__ Wcat,  bf16* __restrict__ GS,
    const bf16* __restrict__ GinCx, const bf16* __restrict__ Zc,
    const bf16* __restrict__ Wcat2, bf16* __restrict__ GC,
    const float* __restrict__ bslot, const float* __restrict__ bcls, int nS)
{
  __shared__ __align__(16) bf16 As[64*64];
  __shared__ __align__(16) bf16 Bs[64*64];
  int wg = xcd_swizzle(blockIdx.x, gridDim.x);
  if (wg < nS) {
    gemm_body<64, 64, 3840, 0, 1536, 3072, 768, 0>(As, Bs, wg, GinSx, Zs, Wcat, GS,
        nullptr, nullptr, nullptr, bslot, nullptr, 0, 0);
  } else {
    gemm_body<64, 64, 2304, 0, 1536, 1536, 768, 0>(As, Bs, wg - nS, GinCx, Zc, Wcat2, GC,
        nullptr, nullptr, nullptr, bcls, nullptr, 0, 0);
  }
}

// ------------------------------------------------------------------
extern "C" void kernel_launch(void* const* d_in, const int* in_sizes, int n_in,
                              void* d_out, int out_size, void* d_ws, size_t ws_size,
                              hipStream_t stream)
{
  const float* slots  = (const float*)d_in[0];
  const float* cls    = (const float*)d_in[1];
  const float* a_cur  = (const float*)d_in[2];
  const float* a_slot = (const float*)d_in[3];
  const float* a_last = (const float*)d_in[4];
  const float* a_dom  = (const float*)d_in[5];
  const float* W_r    = (const float*)d_in[6];
  const float* b_r    = (const float*)d_in[7];
  const float* W_s    = (const float*)d_in[8];
  const float* b_s    = (const float*)d_in[9];
  const float* W_g    = (const float*)d_in[10];
  const float* b_g    = (const float*)d_in[11];
  float* out = (float*)d_out;

  char* base = (char*)d_ws;
  size_t off = 0;
  auto alloc = [&](size_t bytes) -> void* {
    void* r = base + off;
    off = (off + bytes + 255) & ~(size_t)255;
    return r;
  };

  bf16* Wcat   = (bf16*)alloc((size_t)768*3840*2);
  bf16* Wg     = (bf16*)alloc((size_t)768*1536*2);
  bf16* Wcat2  = (bf16*)alloc((size_t)768*2304*2);
  float* bslot = (float*)alloc(768*4);
  float* bcls  = (float*)alloc(768*4);
  size_t fixedOff = off;

  // per-batch: Gin [46x1536] + Zs [30x3072] + Zc [16x1536], bf16.
  // Xo and GinC2 ALIAS into Zs (dead after proj1). chunk in mult of 64.
  const size_t perBatch = (size_t)46*1536*2 + (size_t)30*3072*2 + (size_t)16*1536*2;
  int chunkB = 512;
  while (chunkB > 64 && fixedOff + perBatch*(size_t)chunkB + 65536 > ws_size) chunkB -= 64;

  const int rowsA_a = chunkB * (S_D + C_D);
  bf16* Gin = (bf16*)alloc((size_t)rowsA_a*1536*2);
  bf16* Zs  = (bf16*)alloc((size_t)chunkB*S_D*3072*2);
  bf16* Zc  = (bf16*)alloc((size_t)chunkB*C_D*1536*2);

  {
    int tot = 768*3840 + 768*1536 + 768*2304 + 768;
    prep_weights_k<<<(tot+255)/256, 256, 0, stream>>>(W_r, b_r, W_s, b_s, W_g,
                                                      Wcat, Wg, Wcat2, bslot, bcls);
  }

  for (int b0 = 0; b0 < 512; ) {
    const int cb = (512 - b0 < chunkB) ? (512 - b0) : chunkB;
    const int rows_s = cb * S_D;
    const int rows_c = cb * C_D;
    const int rows_a = cb * (S_D + C_D);
    bf16* GinC  = Gin + (size_t)rows_s*1536;
    bf16* Xo    = Zs;                           // alias (Zs dead post-proj1)
    bf16* XoC   = Xo + (size_t)rows_s*768;
    bf16* GinC2 = Zs + (size_t)rows_a*768;      // alias, disjoint from Xo
    const int nS = (rows_s/64)*12, nC = (rows_c/64)*12;

    // ---- layer 1 ----
    agg1_k<<<cb, 256, 0, stream>>>(slots, cls, a_cur, a_slot, a_last, a_dom,
                                   Gin, Zs, Zc, b0, rows_s);
    // merged slot+cls proj (BM=BN=64: grid 2208, 8 blocks/CU)
    proj1_k<<<nS + nC, 256, 0, stream>>>(Gin + 768, Zs, Wcat, Gin,
                                         GinC + 768, Zc, Wcat2, GinC,
                                         bslot, bcls, nS);
    // gate (all rows): A = Gin = [u | x] -> Xo; cls rows also -> GinC2 right
    gemm_k<64, 64, 1536, 1, 1536, 1536, 1536, 0><<<(rows_a/64)*12, 256, 0, stream>>>(
        Gin, Gin, Wg, Gin, GinC2, Xo, out, bslot, b_g, b0, rows_s);
    // ---- layer 2 (cls rows only; dbuf prefetch) ----
    agg2_k<<<cb, 256, 0, stream>>>(Xo, a_cur, a_last, Zc, b0);
    gemm_k<64, 64, 2304, 0, 1536, 1536, 768, 1><<<nC, 256, 0, stream>>>(
        GinC2 + 768, Zc, Wcat2, GinC2, nullptr, XoC, out, bcls, b_g, b0, 0);
    // final gate -> out
    gemm_k<64, 64, 1536, 2, 1536, 1536, 1536, 1><<<nC, 256, 0, stream>>>(
        GinC2, GinC2, Wg, GinC2, nullptr, XoC, out, bcls, b_g, b0, 0);

    b0 += cb;
  }
}

// Round 17
// 521.853 us; speedup vs baseline: 1.0862x; 1.0862x over previous
//
#include <hip/hip_runtime.h>
#include <hip/hip_bf16.h>
#include <cstdint>
#include <cstddef>

typedef __hip_bfloat16 bf16;
typedef __bf16 bf16x8 __attribute__((ext_vector_type(8)));
typedef float f32x4 __attribute__((ext_vector_type(4)));

#define S_D 30
#define C_D 16
#define H_D 768
#define EPS_F 1e-5f

// ------------------------------------------------------------------
// prep: bf16 transposed weight concats + folded biases.
// K-order PERMUTED to match packed aggregate layout:
// Wcat  [768n x 3840k]: k<768 -> W_s;  k=768+kk*4+seg -> W_r[seg][kk]
// Wcat2 [768n x 2304k]: k<768 -> W_s;  k=768+kk*2+seg -> W_r[seg?2:0][kk]
// Wg    [768n x 1536k]: W_g^T (unpermuted)
// ------------------------------------------------------------------
__global__ __launch_bounds__(256) void prep_weights_k(
    const float* __restrict__ W_r, const float* __restrict__ b_r,
    const float* __restrict__ W_s, const float* __restrict__ b_s,
    const float* __restrict__ W_g,
    bf16* __restrict__ Wcat, bf16* __restrict__ Wg, bf16* __restrict__ Wcat2,
    float* __restrict__ bslot, float* __restrict__ bcls)
{
  int id = blockIdx.x*256 + threadIdx.x;
  const int n1 = 768*3840, n2 = 768*1536, n3 = 768*2304;
  if (id < n1) {
    int n = id / 3840, k = id % 3840;
    float w;
    if (k < 768) w = W_s[k*768 + n];
    else { int j = k - 768, kk = j >> 2, seg = j & 3;
           w = W_r[((size_t)seg*768 + kk)*768 + n]; }
    Wcat[id] = __float2bfloat16(w);
  } else if (id < n1 + n2) {
    int j = id - n1; int n = j / 1536, k = j % 1536;
    Wg[j] = __float2bfloat16(W_g[(size_t)k*768 + n]);
  } else if (id < n1 + n2 + n3) {
    int j = id - n1 - n2; int n = j / 2304, k = j % 2304;
    float w;
    if (k < 768) w = W_s[k*768 + n];
    else { int jj = k - 768, kk = jj >> 1, seg = jj & 1;
           w = W_r[((size_t)(seg ? 2 : 0)*768 + kk)*768 + n]; }
    Wcat2[j] = __float2bfloat16(w);
  } else if (id < n1 + n2 + n3 + 768) {
    int n = id - n1 - n2 - n3;
    bslot[n] = b_s[n] + b_r[n] + b_r[768+n] + b_r[2*768+n] + b_r[3*768+n];
    bcls[n]  = b_s[n] + b_r[n] + b_r[2*768+n];
  }
}

// ------------------------------------------------------------------
// layer-1 aggregation + init (R8 structure, unchanged).
// ------------------------------------------------------------------
__global__ __launch_bounds__(256) void agg1_k(
    const float* __restrict__ slots, const float* __restrict__ cls,
    const float* __restrict__ a_cur, const float* __restrict__ a_slot,
    const float* __restrict__ a_last, const float* __restrict__ a_dom,
    bf16* __restrict__ Gin, bf16* __restrict__ Zs, bf16* __restrict__ Zc,
    int b0, int rsBase)
{
  __shared__ float Lac[30*16], Lal[30*16];
  __shared__ float Las[30*32], Lad[30*32];
  __shared__ float LacT[16*32], LalT[16*32];
  __shared__ float ivr[4*32], ivc[2*16];
  const int lb = blockIdx.x, b = b0 + lb, tid = threadIdx.x;
  const float* ac  = a_cur  + (size_t)b*480;
  const float* as_ = a_slot + (size_t)b*900;
  const float* al  = a_last + (size_t)b*480;
  const float* ad  = a_dom  + (size_t)b*900;

  if (tid < 30) {
    float s1=0, s3=0;
    for (int c=0;c<16;c++){ s1+=ac[tid*16+c]; s3+=al[tid*16+c]; }
    ivr[tid] = 1.f/(s1+EPS_F); ivr[32+tid] = 1.f/(s3+EPS_F);
    float s2=0, s4=0;
    for (int j=0;j<30;j++){ s2+=as_[tid*30+j]; s4+=ad[tid*30+j]; }
    ivr[64+tid] = 1.f/(s2+EPS_F); ivr[96+tid] = 1.f/(s4+EPS_F);
  } else if (tid < 46) {
    int c = tid - 30; float s1=0, s3=0;
    for (int s=0;s<30;s++){ s1+=ac[s*16+c]; s3+=al[s*16+c]; }
    ivc[c] = 1.f/(s1+EPS_F); ivc[16+c] = 1.f/(s3+EPS_F);
  }
  __syncthreads();
  for (int i = tid; i < 480; i += 256) {
    int s = i >> 4;
    Lac[i] = ac[i]*ivr[s];
    Lal[i] = al[i]*ivr[32+s];
  }
  for (int i = tid; i < 960; i += 256) {
    int s = i >> 5, j = i & 31;
    Las[i] = (j < 30) ? as_[s*30+j]*ivr[64+s] : 0.f;
    Lad[i] = (j < 30) ? ad[s*30+j]*ivr[96+s] : 0.f;
  }
  for (int i = tid; i < 512; i += 256) {
    int c = i >> 5, s = i & 31;
    LacT[i] = (s < 30) ? ac[s*16+c]*ivc[c]    : 0.f;
    LalT[i] = (s < 30) ? al[s*16+c]*ivc[16+c] : 0.f;
  }
  __syncthreads();

  float xs[3][32], xc[3][16];
  #pragma unroll
  for (int j = 0; j < 3; ++j) {
    const int h = tid + j*256;
    #pragma unroll
    for (int s = 0; s < 30; ++s) xs[j][s] = slots[((size_t)b*30 + s)*768 + h];
    xs[j][30] = 0.f; xs[j][31] = 0.f;
    #pragma unroll
    for (int c = 0; c < 16; ++c) xc[j][c] = cls[((size_t)b*16 + c)*768 + h];
  }
  #pragma unroll
  for (int j = 0; j < 3; ++j) {
    const int h = tid + j*256;
    bf16* Gs = Gin + ((size_t)lb*30)*1536 + 768 + h;
    #pragma unroll
    for (int s = 0; s < 30; ++s) Gs[(size_t)s*1536] = __float2bfloat16(xs[j][s]);
    bf16* Gc = Gin + ((size_t)(rsBase + lb*16))*1536 + 768 + h;
    #pragma unroll
    for (int c = 0; c < 16; ++c) Gc[(size_t)c*1536] = __float2bfloat16(xc[j][c]);
  }

  #pragma unroll 2
  for (int s = 0; s < 30; ++s) {
    float a1[3] = {}, a2[3] = {}, a3[3] = {}, a4[3] = {};
    #pragma unroll
    for (int q = 0; q < 4; ++q) {
      float4 va = *(const float4*)&Lac[s*16 + q*4];
      float4 vl = *(const float4*)&Lal[s*16 + q*4];
      #pragma unroll
      for (int j = 0; j < 3; ++j) {
        a1[j] += va.x*xc[j][q*4] + va.y*xc[j][q*4+1] + va.z*xc[j][q*4+2] + va.w*xc[j][q*4+3];
        a3[j] += vl.x*xc[j][q*4] + vl.y*xc[j][q*4+1] + vl.z*xc[j][q*4+2] + vl.w*xc[j][q*4+3];
      }
    }
    #pragma unroll
    for (int q = 0; q < 8; ++q) {
      float4 vs = *(const float4*)&Las[s*32 + q*4];
      float4 vd = *(const float4*)&Lad[s*32 + q*4];
      #pragma unroll
      for (int j = 0; j < 3; ++j) {
        a2[j] += vs.x*xs[j][q*4] + vs.y*xs[j][q*4+1] + vs.z*xs[j][q*4+2] + vs.w*xs[j][q*4+3];
        a4[j] += vd.x*xs[j][q*4] + vd.y*xs[j][q*4+1] + vd.z*xs[j][q*4+2] + vd.w*xs[j][q*4+3];
      }
    }
    char* Zrow = (char*)Zs + (((size_t)lb*30 + s)*3072)*2;
    #pragma unroll
    for (int j = 0; j < 3; ++j) {
      const int h = tid + j*256;
      union { bf16 hv[4]; uint2 u; } p;
      p.hv[0] = __float2bfloat16(a1[j]);
      p.hv[1] = __float2bfloat16(a2[j]);
      p.hv[2] = __float2bfloat16(a3[j]);
      p.hv[3] = __float2bfloat16(a4[j]);
      *(uint2*)(Zrow + (size_t)h*8) = p.u;
    }
  }
  #pragma unroll 2
  for (int c = 0; c < 16; ++c) {
    float a1[3] = {}, a3[3] = {};
    #pragma unroll
    for (int q = 0; q < 8; ++q) {
      float4 va = *(const float4*)&LacT[c*32 + q*4];
      float4 vl = *(const float4*)&LalT[c*32 + q*4];
      #pragma unroll
      for (int j = 0; j < 3; ++j) {
        a1[j] += va.x*xs[j][q*4] + va.y*xs[j][q*4+1] + va.z*xs[j][q*4+2] + va.w*xs[j][q*4+3];
        a3[j] += vl.x*xs[j][q*4] + vl.y*xs[j][q*4+1] + vl.z*xs[j][q*4+2] + vl.w*xs[j][q*4+3];
      }
    }
    char* Zrow = (char*)Zc + (((size_t)lb*16 + c)*1536)*2;
    #pragma unroll
    for (int j = 0; j < 3; ++j) {
      const int h = tid + j*256;
      union { bf16 hv[2]; unsigned u; } p;
      p.hv[0] = __float2bfloat16(a1[j]);
      p.hv[1] = __float2bfloat16(a3[j]);
      *(unsigned*)(Zrow + (size_t)h*4) = p.u;
    }
  }
}

// ------------------------------------------------------------------
// layer-2 aggregation (cls rows only) from layer-1 slot state Xo (bf16).
// ------------------------------------------------------------------
__global__ __launch_bounds__(256) void agg2_k(
    const bf16* __restrict__ Xo,
    const float* __restrict__ a_cur, const float* __restrict__ a_last,
    bf16* __restrict__ Zc, int b0)
{
  __shared__ float LacT[16*32], LalT[16*32];
  __shared__ float ivc[2*16];
  const int lb = blockIdx.x, b = b0 + lb, tid = threadIdx.x;
  const float* ac = a_cur  + (size_t)b*480;
  const float* al = a_last + (size_t)b*480;
  if (tid < 16) {
    float s1=0, s3=0;
    for (int s=0;s<30;s++){ s1+=ac[s*16+tid]; s3+=al[s*16+tid]; }
    ivc[tid] = 1.f/(s1+EPS_F); ivc[16+tid] = 1.f/(s3+EPS_F);
  }
  __syncthreads();
  for (int i = tid; i < 512; i += 256) {
    int c = i >> 5, s = i & 31;
    LacT[i] = (s < 30) ? ac[s*16+c]*ivc[c]    : 0.f;
    LalT[i] = (s < 30) ? al[s*16+c]*ivc[16+c] : 0.f;
  }
  __syncthreads();

  float xs[3][32];
  #pragma unroll
  for (int j = 0; j < 3; ++j) {
    const int h = tid + j*256;
    #pragma unroll
    for (int s = 0; s < 30; ++s)
      xs[j][s] = __bfloat162float(Xo[((size_t)(lb*30 + s))*768 + h]);
    xs[j][30] = 0.f; xs[j][31] = 0.f;
  }
  #pragma unroll 2
  for (int c = 0; c < 16; ++c) {
    float a1[3] = {}, a3[3] = {};
    #pragma unroll
    for (int q = 0; q < 8; ++q) {
      float4 va = *(const float4*)&LacT[c*32 + q*4];
      float4 vl = *(const float4*)&LalT[c*32 + q*4];
      #pragma unroll
      for (int j = 0; j < 3; ++j) {
        a1[j] += va.x*xs[j][q*4] + va.y*xs[j][q*4+1] + va.z*xs[j][q*4+2] + va.w*xs[j][q*4+3];
        a3[j] += vl.x*xs[j][q*4] + vl.y*xs[j][q*4+1] + vl.z*xs[j][q*4+2] + vl.w*xs[j][q*4+3];
      }
    }
    char* Zrow = (char*)Zc + (((size_t)lb*16 + c)*1536)*2;
    #pragma unroll
    for (int j = 0; j < 3; ++j) {
      const int h = tid + j*256;
      union { bf16 hv[2]; unsigned u; } p;
      p.hv[0] = __float2bfloat16(a1[j]);
      p.hv[1] = __float2bfloat16(a3[j]);
      *(unsigned*)(Zrow + (size_t)h*4) = p.u;
    }
  }
}

// ------------------------------------------------------------------
// GEMM body: one BMx128 tile (BK=64) of A[M x K] @ Bt[768 x K]^T.
// BM=64/BN=128 (R11/R13 optimum: 24 KB LDS, ~5 blocks/CU cap, B-panel
// reuse keeps traffic L2-friendly). T2 both-sides XOR swizzle.
// MODE 0 = 1buf split-K pointer staging; MODE 1 = legacy dbuf prefetch.
// EPI 0: proj -> G left half = bf16(v + bias[col])
// EPI 1: gate -> Xo bf16; rows>=rsB also G2 right half (new cls x)
// EPI 2: gate -> out f32 (cls rows; skip c==0)
// ------------------------------------------------------------------
template<int BM, int K, int EPI, int LDA0, int LDA1, int SK, int MODE>
__device__ __forceinline__ void gemm_body(
    bf16* __restrict__ As, bf16* __restrict__ Bs, int wg,
    const bf16* __restrict__ A0, const bf16* __restrict__ A1,
    const bf16* __restrict__ Bt, bf16* __restrict__ G,
    bf16* __restrict__ G2, bf16* __restrict__ Xo, float* __restrict__ out,
    const float* __restrict__ bias, const float* __restrict__ bg,
    int b0, int rsB)
{
  constexpr int AM = BM/32;                  // a-frags per wave (= A issues)
  const int tid  = threadIdx.x;
  const int lane = tid & 63;
  const int wave = tid >> 6;
  const int wm = wave >> 1, wn = wave & 1;   // 2x2 wave grid
  const int bm = wg / 6, bn = wg % 6;        // BN=128 -> 6 n-tiles

  const int swz = (((tid & 7) ^ ((tid >> 3) & 7))) << 3;   // elements
  const bf16* Ag0 = A0 + (size_t)(bm*BM + (tid>>3))*LDA0 + swz;
  const bf16* Ag1 = A1 + (size_t)(bm*BM + (tid>>3))*LDA1 + swz;
  const bf16* Bg  = Bt + (size_t)(bn*128 + (tid>>3))*K   + swz;
  const int ldsw = (wave*8)*64;              // wave-uniform LDS base

  f32x4 acc[AM][4] = {};
  constexpr int NT = K/64;

  auto compute = [&](int buf) {
    const bf16* Asb = As + buf*(BM*64);
    const bf16* Bsb = Bs + buf*8192;
    #pragma unroll
    for (int ks = 0; ks < 64; ks += 32) {
      bf16x8 afv[AM], bfv[4];
      const int sa = ((((ks >> 3) + (lane >> 4)) ^ (lane & 7))) << 3;
      #pragma unroll
      for (int i = 0; i < AM; ++i) {
        int m = wm*(BM/2) + i*16 + (lane & 15);
        afv[i] = *(const bf16x8*)&Asb[m*64 + sa];
      }
      #pragma unroll
      for (int j = 0; j < 4; ++j) {
        int n = wn*64 + j*16 + (lane & 15);
        bfv[j] = *(const bf16x8*)&Bsb[n*64 + sa];
      }
      #pragma unroll
      for (int i = 0; i < AM; ++i)
        #pragma unroll
        for (int j = 0; j < 4; ++j)
          acc[i][j] = __builtin_amdgcn_mfma_f32_16x16x32_bf16(afv[i], bfv[j], acc[i][j], 0, 0, 0);
    }
  };

  if constexpr (MODE == 0) {
    // 1buf split-K pointer staging
    const bf16* aP[AM];
    const bf16* bP[4];
    #pragma unroll
    for (int p = 0; p < AM; ++p) aP[p] = Ag0 + (size_t)(p*32)*LDA0;
    #pragma unroll
    for (int p = 0; p < 4; ++p)  bP[p] = Bg + (size_t)(p*32)*K;

    auto step = [&]() {
      #pragma unroll
      for (int p = 0; p < AM; ++p) {
        __builtin_amdgcn_global_load_lds(
          (const __attribute__((address_space(1))) void*)aP[p],
          (__attribute__((address_space(3))) void*)(&As[ldsw + p*2048]), 16, 0, 0);
        aP[p] += 64;
      }
      #pragma unroll
      for (int p = 0; p < 4; ++p) {
        __builtin_amdgcn_global_load_lds(
          (const __attribute__((address_space(1))) void*)bP[p],
          (__attribute__((address_space(3))) void*)(&Bs[ldsw + p*2048]), 16, 0, 0);
        bP[p] += 64;
      }
      __syncthreads();     // loads landed
      compute(0);
      __syncthreads();     // reads done before next overwrite
    };

    #pragma unroll 1
    for (int t = 0; t < SK/64; ++t) step();
    if constexpr (SK < K) {
      #pragma unroll
      for (int p = 0; p < AM; ++p) aP[p] = Ag1 + (size_t)(p*32)*LDA1;
      #pragma unroll 1
      for (int t = 0; t < (K - SK)/64; ++t) step();
    }
  } else {
    // legacy dbuf prefetch (__syncthreads drains) -- small layer-2 grids
    auto stage = [&](int buf, int kt) {
      #pragma unroll
      for (int p = 0; p < AM; ++p) {
        const bf16* asrc = (kt < SK) ? (Ag0 + (size_t)(p*32)*LDA0 + kt)
                                     : (Ag1 + (size_t)(p*32)*LDA1 + (kt - SK));
        __builtin_amdgcn_global_load_lds(
          (const __attribute__((address_space(1))) void*)asrc,
          (__attribute__((address_space(3))) void*)(&As[buf*(BM*64) + ldsw + p*2048]), 16, 0, 0);
      }
      #pragma unroll
      for (int p = 0; p < 4; ++p) {
        __builtin_amdgcn_global_load_lds(
          (const __attribute__((address_space(1))) void*)(Bg + (size_t)(p*32)*K + kt),
          (__attribute__((address_space(3))) void*)(&Bs[buf*8192 + ldsw + p*2048]), 16, 0, 0);
      }
    };
    stage(0, 0);
    __syncthreads();
    int cur = 0;
    #pragma unroll 1
    for (int t = 0; t < NT; ++t) {
      if (t + 1 < NT) stage(cur ^ 1, (t + 1)*64);
      compute(cur);
      __syncthreads();
      cur ^= 1;
    }
  }

  const int rbase = bm*BM + wm*(BM/2) + ((lane>>4)<<2);
  const int cbase = bn*128 + wn*64 + (lane & 15);
  #pragma unroll
  for (int i = 0; i < AM; ++i) {
    #pragma unroll
    for (int j = 0; j < 4; ++j) {
      const int col = cbase + j*16;
      #pragma unroll
      for (int r2 = 0; r2 < 4; ++r2) {
        const int row = rbase + i*16 + r2;
        float v = acc[i][j][r2];
        if constexpr (EPI == 0) {
          G[(size_t)row*1536 + col] = __float2bfloat16(v + bias[col]);
        } else if constexpr (EPI == 1) {
          v += bg[col];
          float g = 1.f/(1.f + __expf(-v));
          float u = __bfloat162float(G[(size_t)row*1536 + col]);
          float x = __bfloat162float(G[(size_t)row*1536 + 768 + col]);
          bf16 nv = __float2bfloat16(fmaxf(u, 0.f)*g + x*(1.f - g));
          Xo[(size_t)row*H_D + col] = nv;
          if (row >= rsB)
            G2[((size_t)(row - rsB))*1536 + 768 + col] = nv;
        } else { // EPI == 2
          v += bg[col];
          float g = 1.f/(1.f + __expf(-v));
          float u = __bfloat162float(G[(size_t)row*1536 + col]);
          int bb = row >> 4, c = row & 15;
          if (c >= 1) {
            float x = __bfloat162float(Xo[(size_t)row*H_D + col]);
            out[((size_t)(b0 + bb)*15 + (c - 1))*H_D + col] =
                fmaxf(u, 0.f)*g + x*(1.f - g);
          }
        }
      }
    }
  }
}

// T1 bijective XCD-chunked swizzle (m204)
__device__ __forceinline__ int xcd_swizzle(int bid, int nwg) {
  const int q = nwg >> 3, r = nwg & 7;
  const int xcd = bid & 7, idx = bid >> 3;
  return (xcd < r ? xcd*(q+1) : r*(q+1) + (xcd-r)*q) + idx;
}

// Standalone GEMM kernel
template<int BM, int K, int EPI, int LDA0, int LDA1, int SK, int MODE>
__global__ __launch_bounds__(256) void gemm_k(
    const bf16* __restrict__ A0, const bf16* __restrict__ A1,
    const bf16* __restrict__ Bt, bf16* __restrict__ G,
    bf16* __restrict__ G2, bf16* __restrict__ Xo, float* __restrict__ out,
    const float* __restrict__ bias, const float* __restrict__ bg,
    int b0, int rsB)
{
  __shared__ __align__(16) bf16 As[(MODE ? 2 : 1)*BM*64];
  __shared__ __align__(16) bf16 Bs[(MODE ? 2 : 1)*128*64];
  int wg = xcd_swizzle(blockIdx.x, gridDim.x);
  gemm_body<BM, K, EPI, LDA0, LDA1, SK, MODE>(As, Bs, wg, A0, A1, Bt, G, G2, Xo,
                                              out, bias, bg, b0, rsB);
}

// Merged layer-1 projection with BALANCED slot/cls interleave: after the
// XCD swizzle, groups of 23 consecutive ids = 15 slot (K=3840, 60 steps)
// + 8 cls (K=2304, 36 steps), matching nS:nC = 30:16 exactly -- every
// XCD gets proportional heavy/light work (R13's chunked swizzle had
// slot on XCDs 0-5 and cls on 6-7: ~40% idle tail on 2 XCDs).
__global__ __launch_bounds__(256) void proj1_k(
    const bf16* __restrict__ GinSx, const bf16* __restrict__ Zs,
    const bf16* __restrict__ Wcat,  bf16* __restrict__ GS,
    const bf16* __restrict__ GinCx, const bf16* __restrict__ Zc,
    const bf16* __restrict__ Wcat2, bf16* __restrict__ GC,
    const float* __restrict__ bslot, const float* __restrict__ bcls, int nS)
{
  __shared__ __align__(16) bf16 As[64*64];
  __shared__ __align__(16) bf16 Bs[128*64];
  int wg = xcd_swizzle(blockIdx.x, gridDim.x);
  int g = wg / 23, r = wg % 23;
  if (r < 15) {
    gemm_body<64, 3840, 0, 1536, 3072, 768, 0>(As, Bs, g*15 + r, GinSx, Zs, Wcat, GS,
        nullptr, nullptr, nullptr, bslot, nullptr, 0, 0);
  } else {
    gemm_body<64, 2304, 0, 1536, 1536, 768, 0>(As, Bs, g*8 + (r - 15), GinCx, Zc, Wcat2, GC,
        nullptr, nullptr, nullptr, bcls, nullptr, 0, 0);
  }
}

// ------------------------------------------------------------------
extern "C" void kernel_launch(void* const* d_in, const int* in_sizes, int n_in,
                              void* d_out, int out_size, void* d_ws, size_t ws_size,
                              hipStream_t stream)
{
  const float* slots  = (const float*)d_in[0];
  const float* cls    = (const float*)d_in[1];
  const float* a_cur  = (const float*)d_in[2];
  const float* a_slot = (const float*)d_in[3];
  const float* a_last = (const float*)d_in[4];
  const float* a_dom  = (const float*)d_in[5];
  const float* W_r    = (const float*)d_in[6];
  const float* b_r    = (const float*)d_in[7];
  const float* W_s    = (const float*)d_in[8];
  const float* b_s    = (const float*)d_in[9];
  const float* W_g    = (const float*)d_in[10];
  const float* b_g    = (const float*)d_in[11];
  float* out = (float*)d_out;

  char* base = (char*)d_ws;
  size_t off = 0;
  auto alloc = [&](size_t bytes) -> void* {
    void* r = base + off;
    off = (off + bytes + 255) & ~(size_t)255;
    return r;
  };

  bf16* Wcat   = (bf16*)alloc((size_t)768*3840*2);
  bf16* Wg     = (bf16*)alloc((size_t)768*1536*2);
  bf16* Wcat2  = (bf16*)alloc((size_t)768*2304*2);
  float* bslot = (float*)alloc(768*4);
  float* bcls  = (float*)alloc(768*4);
  size_t fixedOff = off;

  // per-batch: Gin [46x1536] + Zs [30x3072] + Zc [16x1536], bf16.
  // Xo and GinC2 ALIAS into Zs (dead after proj1). chunk in mult of 64.
  const size_t perBatch = (size_t)46*1536*2 + (size_t)30*3072*2 + (size_t)16*1536*2;
  int chunkB = 512;
  while (chunkB > 64 && fixedOff + perBatch*(size_t)chunkB + 65536 > ws_size) chunkB -= 64;

  const int rowsA_a = chunkB * (S_D + C_D);
  bf16* Gin = (bf16*)alloc((size_t)rowsA_a*1536*2);
  bf16* Zs  = (bf16*)alloc((size_t)chunkB*S_D*3072*2);
  bf16* Zc  = (bf16*)alloc((size_t)chunkB*C_D*1536*2);

  {
    int tot = 768*3840 + 768*1536 + 768*2304 + 768;
    prep_weights_k<<<(tot+255)/256, 256, 0, stream>>>(W_r, b_r, W_s, b_s, W_g,
                                                      Wcat, Wg, Wcat2, bslot, bcls);
  }

  for (int b0 = 0; b0 < 512; ) {
    const int cb = (512 - b0 < chunkB) ? (512 - b0) : chunkB;
    const int rows_s = cb * S_D;
    const int rows_c = cb * C_D;
    const int rows_a = cb * (S_D + C_D);
    bf16* GinC  = Gin + (size_t)rows_s*1536;
    bf16* Xo    = Zs;                           // alias (Zs dead post-proj1)
    bf16* XoC   = Xo + (size_t)rows_s*768;
    bf16* GinC2 = Zs + (size_t)rows_a*768;      // alias, disjoint from Xo
    const int nS = (rows_s/64)*6, nC = (rows_c/64)*6;

    // ---- layer 1 ----
    agg1_k<<<cb, 256, 0, stream>>>(slots, cls, a_cur, a_slot, a_last, a_dom,
                                   Gin, Zs, Zc, b0, rows_s);
    // merged slot+cls proj, balanced 15:8 interleave across XCDs
    proj1_k<<<nS + nC, 256, 0, stream>>>(Gin + 768, Zs, Wcat, Gin,
                                         GinC + 768, Zc, Wcat2, GinC,
                                         bslot, bcls, nS);
    // gate (all rows): A = Gin = [u | x] -> Xo; cls rows also -> GinC2 right
    gemm_k<64, 1536, 1, 1536, 1536, 1536, 0><<<(rows_a/64)*6, 256, 0, stream>>>(
        Gin, Gin, Wg, Gin, GinC2, Xo, out, bslot, b_g, b0, rows_s);
    // ---- layer 2 (cls rows only; dbuf prefetch) ----
    agg2_k<<<cb, 256, 0, stream>>>(Xo, a_cur, a_last, Zc, b0);
    gemm_k<64, 2304, 0, 1536, 1536, 768, 1><<<nC, 256, 0, stream>>>(
        GinC2 + 768, Zc, Wcat2, GinC2, nullptr, XoC, out, bcls, b_g, b0, 0);
    // final gate -> out
    gemm_k<64, 1536, 2, 1536, 1536, 1536, 1><<<nC, 256, 0, stream>>>(
        GinC2, GinC2, Wg, GinC2, nullptr, XoC, out, bcls, b_g, b0, 0);

    b0 += cb;
  }
}

// Round 18
// 502.781 us; speedup vs baseline: 1.1274x; 1.0379x over previous
//
#include <hip/hip_runtime.h>
#include <hip/hip_bf16.h>
#include <cstdint>
#include <cstddef>

typedef __hip_bfloat16 bf16;
typedef __bf16 bf16x8 __attribute__((ext_vector_type(8)));
typedef float f32x4 __attribute__((ext_vector_type(4)));

#define S_D 30
#define C_D 16
#define H_D 768
#define EPS_F 1e-5f

// ------------------------------------------------------------------
// prep: bf16 transposed weight concats + folded biases.
// K-order PERMUTED to match packed aggregate layout:
// Wcat  [768n x 3840k]: k<768 -> W_s;  k=768+kk*4+seg -> W_r[seg][kk]
// Wcat2 [768n x 2304k]: k<768 -> W_s;  k=768+kk*2+seg -> W_r[seg?2:0][kk]
// Wg    [768n x 1536k]: W_g^T (unpermuted)
// ------------------------------------------------------------------
__global__ __launch_bounds__(256) void prep_weights_k(
    const float* __restrict__ W_r, const float* __restrict__ b_r,
    const float* __restrict__ W_s, const float* __restrict__ b_s,
    const float* __restrict__ W_g,
    bf16* __restrict__ Wcat, bf16* __restrict__ Wg, bf16* __restrict__ Wcat2,
    float* __restrict__ bslot, float* __restrict__ bcls)
{
  int id = blockIdx.x*256 + threadIdx.x;
  const int n1 = 768*3840, n2 = 768*1536, n3 = 768*2304;
  if (id < n1) {
    int n = id / 3840, k = id % 3840;
    float w;
    if (k < 768) w = W_s[k*768 + n];
    else { int j = k - 768, kk = j >> 2, seg = j & 3;
           w = W_r[((size_t)seg*768 + kk)*768 + n]; }
    Wcat[id] = __float2bfloat16(w);
  } else if (id < n1 + n2) {
    int j = id - n1; int n = j / 1536, k = j % 1536;
    Wg[j] = __float2bfloat16(W_g[(size_t)k*768 + n]);
  } else if (id < n1 + n2 + n3) {
    int j = id - n1 - n2; int n = j / 2304, k = j % 2304;
    float w;
    if (k < 768) w = W_s[k*768 + n];
    else { int jj = k - 768, kk = jj >> 1, seg = jj & 1;
           w = W_r[((size_t)(seg ? 2 : 0)*768 + kk)*768 + n]; }
    Wcat2[j] = __float2bfloat16(w);
  } else if (id < n1 + n2 + n3 + 768) {
    int n = id - n1 - n2 - n3;
    bslot[n] = b_s[n] + b_r[n] + b_r[768+n] + b_r[2*768+n] + b_r[3*768+n];
    bcls[n]  = b_s[n] + b_r[n] + b_r[2*768+n];
  }
}

// ------------------------------------------------------------------
// layer-1 aggregation + init (R8 structure, unchanged).
// ------------------------------------------------------------------
__global__ __launch_bounds__(256) void agg1_k(
    const float* __restrict__ slots, const float* __restrict__ cls,
    const float* __restrict__ a_cur, const float* __restrict__ a_slot,
    const float* __restrict__ a_last, const float* __restrict__ a_dom,
    bf16* __restrict__ Gin, bf16* __restrict__ Zs, bf16* __restrict__ Zc,
    int b0, int rsBase)
{
  __shared__ float Lac[30*16], Lal[30*16];
  __shared__ float Las[30*32], Lad[30*32];
  __shared__ float LacT[16*32], LalT[16*32];
  __shared__ float ivr[4*32], ivc[2*16];
  const int lb = blockIdx.x, b = b0 + lb, tid = threadIdx.x;
  const float* ac  = a_cur  + (size_t)b*480;
  const float* as_ = a_slot + (size_t)b*900;
  const float* al  = a_last + (size_t)b*480;
  const float* ad  = a_dom  + (size_t)b*900;

  if (tid < 30) {
    float s1=0, s3=0;
    for (int c=0;c<16;c++){ s1+=ac[tid*16+c]; s3+=al[tid*16+c]; }
    ivr[tid] = 1.f/(s1+EPS_F); ivr[32+tid] = 1.f/(s3+EPS_F);
    float s2=0, s4=0;
    for (int j=0;j<30;j++){ s2+=as_[tid*30+j]; s4+=ad[tid*30+j]; }
    ivr[64+tid] = 1.f/(s2+EPS_F); ivr[96+tid] = 1.f/(s4+EPS_F);
  } else if (tid < 46) {
    int c = tid - 30; float s1=0, s3=0;
    for (int s=0;s<30;s++){ s1+=ac[s*16+c]; s3+=al[s*16+c]; }
    ivc[c] = 1.f/(s1+EPS_F); ivc[16+c] = 1.f/(s3+EPS_F);
  }
  __syncthreads();
  for (int i = tid; i < 480; i += 256) {
    int s = i >> 4;
    Lac[i] = ac[i]*ivr[s];
    Lal[i] = al[i]*ivr[32+s];
  }
  for (int i = tid; i < 960; i += 256) {
    int s = i >> 5, j = i & 31;
    Las[i] = (j < 30) ? as_[s*30+j]*ivr[64+s] : 0.f;
    Lad[i] = (j < 30) ? ad[s*30+j]*ivr[96+s] : 0.f;
  }
  for (int i = tid; i < 512; i += 256) {
    int c = i >> 5, s = i & 31;
    LacT[i] = (s < 30) ? ac[s*16+c]*ivc[c]    : 0.f;
    LalT[i] = (s < 30) ? al[s*16+c]*ivc[16+c] : 0.f;
  }
  __syncthreads();

  float xs[3][32], xc[3][16];
  #pragma unroll
  for (int j = 0; j < 3; ++j) {
    const int h = tid + j*256;
    #pragma unroll
    for (int s = 0; s < 30; ++s) xs[j][s] = slots[((size_t)b*30 + s)*768 + h];
    xs[j][30] = 0.f; xs[j][31] = 0.f;
    #pragma unroll
    for (int c = 0; c < 16; ++c) xc[j][c] = cls[((size_t)b*16 + c)*768 + h];
  }
  #pragma unroll
  for (int j = 0; j < 3; ++j) {
    const int h = tid + j*256;
    bf16* Gs = Gin + ((size_t)lb*30)*1536 + 768 + h;
    #pragma unroll
    for (int s = 0; s < 30; ++s) Gs[(size_t)s*1536] = __float2bfloat16(xs[j][s]);
    bf16* Gc = Gin + ((size_t)(rsBase + lb*16))*1536 + 768 + h;
    #pragma unroll
    for (int c = 0; c < 16; ++c) Gc[(size_t)c*1536] = __float2bfloat16(xc[j][c]);
  }

  #pragma unroll 2
  for (int s = 0; s < 30; ++s) {
    float a1[3] = {}, a2[3] = {}, a3[3] = {}, a4[3] = {};
    #pragma unroll
    for (int q = 0; q < 4; ++q) {
      float4 va = *(const float4*)&Lac[s*16 + q*4];
      float4 vl = *(const float4*)&Lal[s*16 + q*4];
      #pragma unroll
      for (int j = 0; j < 3; ++j) {
        a1[j] += va.x*xc[j][q*4] + va.y*xc[j][q*4+1] + va.z*xc[j][q*4+2] + va.w*xc[j][q*4+3];
        a3[j] += vl.x*xc[j][q*4] + vl.y*xc[j][q*4+1] + vl.z*xc[j][q*4+2] + vl.w*xc[j][q*4+3];
      }
    }
    #pragma unroll
    for (int q = 0; q < 8; ++q) {
      float4 vs = *(const float4*)&Las[s*32 + q*4];
      float4 vd = *(const float4*)&Lad[s*32 + q*4];
      #pragma unroll
      for (int j = 0; j < 3; ++j) {
        a2[j] += vs.x*xs[j][q*4] + vs.y*xs[j][q*4+1] + vs.z*xs[j][q*4+2] + vs.w*xs[j][q*4+3];
        a4[j] += vd.x*xs[j][q*4] + vd.y*xs[j][q*4+1] + vd.z*xs[j][q*4+2] + vd.w*xs[j][q*4+3];
      }
    }
    char* Zrow = (char*)Zs + (((size_t)lb*30 + s)*3072)*2;
    #pragma unroll
    for (int j = 0; j < 3; ++j) {
      const int h = tid + j*256;
      union { bf16 hv[4]; uint2 u; } p;
      p.hv[0] = __float2bfloat16(a1[j]);
      p.hv[1] = __float2bfloat16(a2[j]);
      p.hv[2] = __float2bfloat16(a3[j]);
      p.hv[3] = __float2bfloat16(a4[j]);
      *(uint2*)(Zrow + (size_t)h*8) = p.u;
    }
  }
  #pragma unroll 2
  for (int c = 0; c < 16; ++c) {
    float a1[3] = {}, a3[3] = {};
    #pragma unroll
    for (int q = 0; q < 8; ++q) {
      float4 va = *(const float4*)&LacT[c*32 + q*4];
      float4 vl = *(const float4*)&LalT[c*32 + q*4];
      #pragma unroll
      for (int j = 0; j < 3; ++j) {
        a1[j] += va.x*xs[j][q*4] + va.y*xs[j][q*4+1] + va.z*xs[j][q*4+2] + va.w*xs[j][q*4+3];
        a3[j] += vl.x*xs[j][q*4] + vl.y*xs[j][q*4+1] + vl.z*xs[j][q*4+2] + vl.w*xs[j][q*4+3];
      }
    }
    char* Zrow = (char*)Zc + (((size_t)lb*16 + c)*1536)*2;
    #pragma unroll
    for (int j = 0; j < 3; ++j) {
      const int h = tid + j*256;
      union { bf16 hv[2]; unsigned u; } p;
      p.hv[0] = __float2bfloat16(a1[j]);
      p.hv[1] = __float2bfloat16(a3[j]);
      *(unsigned*)(Zrow + (size_t)h*4) = p.u;
    }
  }
}

// ------------------------------------------------------------------
// layer-2 aggregation (cls rows only) from layer-1 slot state Xo (bf16).
// ------------------------------------------------------------------
__global__ __launch_bounds__(256) void agg2_k(
    const bf16* __restrict__ Xo,
    const float* __restrict__ a_cur, const float* __restrict__ a_last,
    bf16* __restrict__ Zc, int b0)
{
  __shared__ float LacT[16*32], LalT[16*32];
  __shared__ float ivc[2*16];
  const int lb = blockIdx.x, b = b0 + lb, tid = threadIdx.x;
  const float* ac = a_cur  + (size_t)b*480;
  const float* al = a_last + (size_t)b*480;
  if (tid < 16) {
    float s1=0, s3=0;
    for (int s=0;s<30;s++){ s1+=ac[s*16+tid]; s3+=al[s*16+tid]; }
    ivc[tid] = 1.f/(s1+EPS_F); ivc[16+tid] = 1.f/(s3+EPS_F);
  }
  __syncthreads();
  for (int i = tid; i < 512; i += 256) {
    int c = i >> 5, s = i & 31;
    LacT[i] = (s < 30) ? ac[s*16+c]*ivc[c]    : 0.f;
    LalT[i] = (s < 30) ? al[s*16+c]*ivc[16+c] : 0.f;
  }
  __syncthreads();

  float xs[3][32];
  #pragma unroll
  for (int j = 0; j < 3; ++j) {
    const int h = tid + j*256;
    #pragma unroll
    for (int s = 0; s < 30; ++s)
      xs[j][s] = __bfloat162float(Xo[((size_t)(lb*30 + s))*768 + h]);
    xs[j][30] = 0.f; xs[j][31] = 0.f;
  }
  #pragma unroll 2
  for (int c = 0; c < 16; ++c) {
    float a1[3] = {}, a3[3] = {};
    #pragma unroll
    for (int q = 0; q < 8; ++q) {
      float4 va = *(const float4*)&LacT[c*32 + q*4];
      float4 vl = *(const float4*)&LalT[c*32 + q*4];
      #pragma unroll
      for (int j = 0; j < 3; ++j) {
        a1[j] += va.x*xs[j][q*4] + va.y*xs[j][q*4+1] + va.z*xs[j][q*4+2] + va.w*xs[j][q*4+3];
        a3[j] += vl.x*xs[j][q*4] + vl.y*xs[j][q*4+1] + vl.z*xs[j][q*4+2] + vl.w*xs[j][q*4+3];
      }
    }
    char* Zrow = (char*)Zc + (((size_t)lb*16 + c)*1536)*2;
    #pragma unroll
    for (int j = 0; j < 3; ++j) {
      const int h = tid + j*256;
      union { bf16 hv[2]; unsigned u; } p;
      p.hv[0] = __float2bfloat16(a1[j]);
      p.hv[1] = __float2bfloat16(a3[j]);
      *(unsigned*)(Zrow + (size_t)h*4) = p.u;
    }
  }
}

// ------------------------------------------------------------------
// GEMM body: one BMx128 tile (BK=64) of A[M x K] @ Bt[768 x K]^T.
// BM=64/BN=128 (R11/R13 optimum). T2 both-sides XOR swizzle.
// MODE 0 = 1buf split-K pointer staging; MODE 1 = legacy dbuf prefetch.
// EPI 0: proj -> G left half = bf16(v + bias[col])
// EPI 1: gate -> Xo bf16; rows>=rsB also G2 right half (new cls x)
// EPI 2: gate -> out f32 (cls rows; skip c==0)
// ------------------------------------------------------------------
template<int BM, int K, int EPI, int LDA0, int LDA1, int SK, int MODE>
__device__ __forceinline__ void gemm_body(
    bf16* __restrict__ As, bf16* __restrict__ Bs, int wg,
    const bf16* __restrict__ A0, const bf16* __restrict__ A1,
    const bf16* __restrict__ Bt, bf16* __restrict__ G,
    bf16* __restrict__ G2, bf16* __restrict__ Xo, float* __restrict__ out,
    const float* __restrict__ bias, const float* __restrict__ bg,
    int b0, int rsB)
{
  constexpr int AM = BM/32;                  // a-frags per wave (= A issues)
  const int tid  = threadIdx.x;
  const int lane = tid & 63;
  const int wave = tid >> 6;
  const int wm = wave >> 1, wn = wave & 1;   // 2x2 wave grid
  const int bm = wg / 6, bn = wg % 6;        // BN=128 -> 6 n-tiles

  const int swz = (((tid & 7) ^ ((tid >> 3) & 7))) << 3;   // elements
  const bf16* Ag0 = A0 + (size_t)(bm*BM + (tid>>3))*LDA0 + swz;
  const bf16* Ag1 = A1 + (size_t)(bm*BM + (tid>>3))*LDA1 + swz;
  const bf16* Bg  = Bt + (size_t)(bn*128 + (tid>>3))*K   + swz;
  const int ldsw = (wave*8)*64;              // wave-uniform LDS base

  f32x4 acc[AM][4] = {};
  constexpr int NT = K/64;

  auto compute = [&](int buf) {
    const bf16* Asb = As + buf*(BM*64);
    const bf16* Bsb = Bs + buf*8192;
    #pragma unroll
    for (int ks = 0; ks < 64; ks += 32) {
      bf16x8 afv[AM], bfv[4];
      const int sa = ((((ks >> 3) + (lane >> 4)) ^ (lane & 7))) << 3;
      #pragma unroll
      for (int i = 0; i < AM; ++i) {
        int m = wm*(BM/2) + i*16 + (lane & 15);
        afv[i] = *(const bf16x8*)&Asb[m*64 + sa];
      }
      #pragma unroll
      for (int j = 0; j < 4; ++j) {
        int n = wn*64 + j*16 + (lane & 15);
        bfv[j] = *(const bf16x8*)&Bsb[n*64 + sa];
      }
      #pragma unroll
      for (int i = 0; i < AM; ++i)
        #pragma unroll
        for (int j = 0; j < 4; ++j)
          acc[i][j] = __builtin_amdgcn_mfma_f32_16x16x32_bf16(afv[i], bfv[j], acc[i][j], 0, 0, 0);
    }
  };

  if constexpr (MODE == 0) {
    // 1buf split-K pointer staging
    const bf16* aP[AM];
    const bf16* bP[4];
    #pragma unroll
    for (int p = 0; p < AM; ++p) aP[p] = Ag0 + (size_t)(p*32)*LDA0;
    #pragma unroll
    for (int p = 0; p < 4; ++p)  bP[p] = Bg + (size_t)(p*32)*K;

    auto step = [&]() {
      #pragma unroll
      for (int p = 0; p < AM; ++p) {
        __builtin_amdgcn_global_load_lds(
          (const __attribute__((address_space(1))) void*)aP[p],
          (__attribute__((address_space(3))) void*)(&As[ldsw + p*2048]), 16, 0, 0);
        aP[p] += 64;
      }
      #pragma unroll
      for (int p = 0; p < 4; ++p) {
        __builtin_amdgcn_global_load_lds(
          (const __attribute__((address_space(1))) void*)bP[p],
          (__attribute__((address_space(3))) void*)(&Bs[ldsw + p*2048]), 16, 0, 0);
        bP[p] += 64;
      }
      __syncthreads();     // loads landed
      compute(0);
      __syncthreads();     // reads done before next overwrite
    };

    #pragma unroll 1
    for (int t = 0; t < SK/64; ++t) step();
    if constexpr (SK < K) {
      #pragma unroll
      for (int p = 0; p < AM; ++p) aP[p] = Ag1 + (size_t)(p*32)*LDA1;
      #pragma unroll 1
      for (int t = 0; t < (K - SK)/64; ++t) step();
    }
  } else {
    // legacy dbuf prefetch (__syncthreads drains) -- small layer-2 grids
    auto stage = [&](int buf, int kt) {
      #pragma unroll
      for (int p = 0; p < AM; ++p) {
        const bf16* asrc = (kt < SK) ? (Ag0 + (size_t)(p*32)*LDA0 + kt)
                                     : (Ag1 + (size_t)(p*32)*LDA1 + (kt - SK));
        __builtin_amdgcn_global_load_lds(
          (const __attribute__((address_space(1))) void*)asrc,
          (__attribute__((address_space(3))) void*)(&As[buf*(BM*64) + ldsw + p*2048]), 16, 0, 0);
      }
      #pragma unroll
      for (int p = 0; p < 4; ++p) {
        __builtin_amdgcn_global_load_lds(
          (const __attribute__((address_space(1))) void*)(Bg + (size_t)(p*32)*K + kt),
          (__attribute__((address_space(3))) void*)(&Bs[buf*8192 + ldsw + p*2048]), 16, 0, 0);
      }
    };
    stage(0, 0);
    __syncthreads();
    int cur = 0;
    #pragma unroll 1
    for (int t = 0; t < NT; ++t) {
      if (t + 1 < NT) stage(cur ^ 1, (t + 1)*64);
      compute(cur);
      __syncthreads();
      cur ^= 1;
    }
  }

  const int rbase = bm*BM + wm*(BM/2) + ((lane>>4)<<2);
  const int cbase = bn*128 + wn*64 + (lane & 15);
  #pragma unroll
  for (int i = 0; i < AM; ++i) {
    #pragma unroll
    for (int j = 0; j < 4; ++j) {
      const int col = cbase + j*16;
      #pragma unroll
      for (int r2 = 0; r2 < 4; ++r2) {
        const int row = rbase + i*16 + r2;
        float v = acc[i][j][r2];
        if constexpr (EPI == 0) {
          G[(size_t)row*1536 + col] = __float2bfloat16(v + bias[col]);
        } else if constexpr (EPI == 1) {
          v += bg[col];
          float g = 1.f/(1.f + __expf(-v));
          float u = __bfloat162float(G[(size_t)row*1536 + col]);
          float x = __bfloat162float(G[(size_t)row*1536 + 768 + col]);
          bf16 nv = __float2bfloat16(fmaxf(u, 0.f)*g + x*(1.f - g));
          Xo[(size_t)row*H_D + col] = nv;
          if (row >= rsB)
            G2[((size_t)(row - rsB))*1536 + 768 + col] = nv;
        } else { // EPI == 2
          v += bg[col];
          float g = 1.f/(1.f + __expf(-v));
          float u = __bfloat162float(G[(size_t)row*1536 + col]);
          int bb = row >> 4, c = row & 15;
          if (c >= 1) {
            float x = __bfloat162float(Xo[(size_t)row*H_D + col]);
            out[((size_t)(b0 + bb)*15 + (c - 1))*H_D + col] =
                fmaxf(u, 0.f)*g + x*(1.f - g);
          }
        }
      }
    }
  }
}

// T1 bijective XCD-chunked swizzle (m204)
__device__ __forceinline__ int xcd_swizzle(int bid, int nwg) {
  const int q = nwg >> 3, r = nwg & 7;
  const int xcd = bid & 7, idx = bid >> 3;
  return (xcd < r ? xcd*(q+1) : r*(q+1) + (xcd-r)*q) + idx;
}

// Standalone GEMM kernel
template<int BM, int K, int EPI, int LDA0, int LDA1, int SK, int MODE>
__global__ __launch_bounds__(256) void gemm_k(
    const bf16* __restrict__ A0, const bf16* __restrict__ A1,
    const bf16* __restrict__ Bt, bf16* __restrict__ G,
    bf16* __restrict__ G2, bf16* __restrict__ Xo, float* __restrict__ out,
    const float* __restrict__ bias, const float* __restrict__ bg,
    int b0, int rsB)
{
  __shared__ __align__(16) bf16 As[(MODE ? 2 : 1)*BM*64];
  __shared__ __align__(16) bf16 Bs[(MODE ? 2 : 1)*128*64];
  int wg = xcd_swizzle(blockIdx.x, gridDim.x);
  gemm_body<BM, K, EPI, LDA0, LDA1, SK, MODE>(As, Bs, wg, A0, A1, Bt, G, G2, Xo,
                                              out, bias, bg, b0, rsB);
}

// Merged layer-1 projection (R13 assignment: chunked swizzle, slot
// blocks [0,nS) then cls blocks [nS,nS+nC) -- keeps each XCD's B
// working set to ONE weight matrix; the R17 balanced interleave put
// both Wcat+Wcat2 in every XCD's L2 and thrashed, FETCH 240->470 MB).
__global__ __launch_bounds__(256) void proj1_k(
    const bf16* __restrict__ GinSx, const bf16* __restrict__ Zs,
    const bf16* __restrict__ Wcat,  bf16* __restrict__ GS,
    const bf16* __restrict__ GinCx, const bf16* __restrict__ Zc,
    const bf16* __restrict__ Wcat2, bf16* __restrict__ GC,
    const float* __restrict__ bslot, const float* __restrict__ bcls, int nS)
{
  __shared__ __align__(16) bf16 As[64*64];
  __shared__ __align__(16) bf16 Bs[128*64];
  int wg = xcd_swizzle(blockIdx.x, gridDim.x);
  if (wg < nS) {
    gemm_body<64, 3840, 0, 1536, 3072, 768, 0>(As, Bs, wg, GinSx, Zs, Wcat, GS,
        nullptr, nullptr, nullptr, bslot, nullptr, 0, 0);
  } else {
    gemm_body<64, 2304, 0, 1536, 1536, 768, 0>(As, Bs, wg - nS, GinCx, Zc, Wcat2, GC,
        nullptr, nullptr, nullptr, bcls, nullptr, 0, 0);
  }
}

// ------------------------------------------------------------------
extern "C" void kernel_launch(void* const* d_in, const int* in_sizes, int n_in,
                              void* d_out, int out_size, void* d_ws, size_t ws_size,
                              hipStream_t stream)
{
  const float* slots  = (const float*)d_in[0];
  const float* cls    = (const float*)d_in[1];
  const float* a_cur  = (const float*)d_in[2];
  const float* a_slot = (const float*)d_in[3];
  const float* a_last = (const float*)d_in[4];
  const float* a_dom  = (const float*)d_in[5];
  const float* W_r    = (const float*)d_in[6];
  const float* b_r    = (const float*)d_in[7];
  const float* W_s    = (const float*)d_in[8];
  const float* b_s    = (const float*)d_in[9];
  const float* W_g    = (const float*)d_in[10];
  const float* b_g    = (const float*)d_in[11];
  float* out = (float*)d_out;

  char* base = (char*)d_ws;
  size_t off = 0;
  auto alloc = [&](size_t bytes) -> void* {
    void* r = base + off;
    off = (off + bytes + 255) & ~(size_t)255;
    return r;
  };

  bf16* Wcat   = (bf16*)alloc((size_t)768*3840*2);
  bf16* Wg     = (bf16*)alloc((size_t)768*1536*2);
  bf16* Wcat2  = (bf16*)alloc((size_t)768*2304*2);
  float* bslot = (float*)alloc(768*4);
  float* bcls  = (float*)alloc(768*4);
  size_t fixedOff = off;

  // per-batch: Gin [46x1536] + Zs [30x3072] + Zc [16x1536], bf16.
  // Xo and GinC2 ALIAS into Zs (dead after proj1). chunk in mult of 64.
  const size_t perBatch = (size_t)46*1536*2 + (size_t)30*3072*2 + (size_t)16*1536*2;
  int chunkB = 512;
  while (chunkB > 64 && fixedOff + perBatch*(size_t)chunkB + 65536 > ws_size) chunkB -= 64;

  const int rowsA_a = chunkB * (S_D + C_D);
  bf16* Gin = (bf16*)alloc((size_t)rowsA_a*1536*2);
  bf16* Zs  = (bf16*)alloc((size_t)chunkB*S_D*3072*2);
  bf16* Zc  = (bf16*)alloc((size_t)chunkB*C_D*1536*2);

  {
    int tot = 768*3840 + 768*1536 + 768*2304 + 768;
    prep_weights_k<<<(tot+255)/256, 256, 0, stream>>>(W_r, b_r, W_s, b_s, W_g,
                                                      Wcat, Wg, Wcat2, bslot, bcls);
  }

  for (int b0 = 0; b0 < 512; ) {
    const int cb = (512 - b0 < chunkB) ? (512 - b0) : chunkB;
    const int rows_s = cb * S_D;
    const int rows_c = cb * C_D;
    const int rows_a = cb * (S_D + C_D);
    bf16* GinC  = Gin + (size_t)rows_s*1536;
    bf16* Xo    = Zs;                           // alias (Zs dead post-proj1)
    bf16* XoC   = Xo + (size_t)rows_s*768;
    bf16* GinC2 = Zs + (size_t)rows_a*768;      // alias, disjoint from Xo
    const int nS = (rows_s/64)*6, nC = (rows_c/64)*6;

    // ---- layer 1 ----
    agg1_k<<<cb, 256, 0, stream>>>(slots, cls, a_cur, a_slot, a_last, a_dom,
                                   Gin, Zs, Zc, b0, rows_s);
    // merged slot+cls proj (chunked assignment, BM=64/BN=128, 1buf)
    proj1_k<<<nS + nC, 256, 0, stream>>>(Gin + 768, Zs, Wcat, Gin,
                                         GinC + 768, Zc, Wcat2, GinC,
                                         bslot, bcls, nS);
    // gate (all rows): A = Gin = [u | x] -> Xo; cls rows also -> GinC2 right
    gemm_k<64, 1536, 1, 1536, 1536, 1536, 0><<<(rows_a/64)*6, 256, 0, stream>>>(
        Gin, Gin, Wg, Gin, GinC2, Xo, out, bslot, b_g, b0, rows_s);
    // ---- layer 2 (cls rows only; dbuf prefetch) ----
    agg2_k<<<cb, 256, 0, stream>>>(Xo, a_cur, a_last, Zc, b0);
    gemm_k<64, 2304, 0, 1536, 1536, 768, 1><<<nC, 256, 0, stream>>>(
        GinC2 + 768, Zc, Wcat2, GinC2, nullptr, XoC, out, bcls, b_g, b0, 0);
    // final gate -> out
    gemm_k<64, 1536, 2, 1536, 1536, 1536, 1><<<nC, 256, 0, stream>>>(
        GinC2, GinC2, Wg, GinC2, nullptr, XoC, out, bcls, b_g, b0, 0);

    b0 += cb;
  }
}